// Round 5
// baseline (255.777 us; speedup 1.0000x reference)
//
#include <hip/hip_runtime.h>
#include <hip/hip_bf16.h>
#include <math.h>

// Problem constants (from reference)
#define NCLS 100     // NUM_CLASSES
#define DD   128     // D
#define VQD  64      // VQ_DIM
#define VQK  512     // VQ_K

typedef float f32x4 __attribute__((ext_vector_type(4)));

__device__ __forceinline__ float sigmoidf_(float x) { return 1.0f / (1.0f + expf(-x)); }

// ---------------------------------------------------------------------------
// Kernel 1: full forward for each of the 100 classes. One block per class,
// 128 threads. All weights are L2-resident (~0.4 MB total).
// Block 0 also zero-inits the histogram counters (precedes hist kernel in
// stream order).
// ---------------------------------------------------------------------------
__global__ __launch_bounds__(128) void class_forward(
    const float* __restrict__ embed,
    const float* __restrict__ W0, const float* __restrict__ b0,
    const float* __restrict__ W1, const float* __restrict__ b1,
    const float* __restrict__ W2, const float* __restrict__ b2,
    const float* __restrict__ Wp, const float* __restrict__ bp,
    const float* __restrict__ vq,
    const float* __restrict__ Wa, const float* __restrict__ ba,
    const float* __restrict__ Ws, const float* __restrict__ bs,
    const float* __restrict__ Wc0, const float* __restrict__ bc0,
    const float* __restrict__ Wc1, const float* __restrict__ bc1,
    const float* __restrict__ Wc2, const float* __restrict__ bc2,
    const float* __restrict__ Wc3, const float* __restrict__ bc3,
    float* __restrict__ am_c, float* __restrict__ sd_c,
    float* __restrict__ cr_c, float* __restrict__ ms_c, int* __restrict__ id_c,
    unsigned int* __restrict__ counts)
{
    __shared__ float ya[128], za[128], q64[64], qs[64], red[128];
    __shared__ int   redi[128];
    const int c = blockIdx.x;
    const int t = threadIdx.x;

    if (c == 0 && t < NCLS) counts[t] = 0u;

    // embedding lookup
    ya[t] = embed[c * DD + t];
    __syncthreads();

    // 3x dense(128->128) + relu
    float acc = b0[t];
    #pragma unroll 16
    for (int k = 0; k < 128; ++k) acc = fmaf(ya[k], W0[k * 128 + t], acc);
    za[t] = fmaxf(acc, 0.0f);
    __syncthreads();

    acc = b1[t];
    #pragma unroll 16
    for (int k = 0; k < 128; ++k) acc = fmaf(za[k], W1[k * 128 + t], acc);
    ya[t] = fmaxf(acc, 0.0f);
    __syncthreads();

    acc = b2[t];
    #pragma unroll 16
    for (int k = 0; k < 128; ++k) acc = fmaf(ya[k], W2[k * 128 + t], acc);
    za[t] = fmaxf(acc, 0.0f);
    __syncthreads();

    // projection 128 -> 64 (no activation)
    if (t < 64) {
        float a2 = bp[t];
        #pragma unroll 16
        for (int k = 0; k < 128; ++k) a2 = fmaf(za[k], Wp[k * 64 + t], a2);
        q64[t] = a2;
    }
    __syncthreads();

    // ||z||^2 (constant per row, but reference includes it in the argmin key)
    if (t < 64) { red[t] = q64[t] * q64[t]; } else red[t] = 0.0f;
    __syncthreads();
    for (int s = 64; s > 0; s >>= 1) { if (t < s) red[t] += red[t + s]; __syncthreads(); }
    const float zz = red[0];
    __syncthreads();

    // VQ argmin over 512 codes; full key d = (zz - 2 z.e) + ||e||^2 (reference order)
    float bestv = 3.4e38f;
    int   besti = 0;
    for (int cc = t; cc < VQK; cc += 128) {
        const float* e = vq + cc * VQD;
        float dot = 0.0f, esq = 0.0f;
        #pragma unroll 16
        for (int k = 0; k < VQD; ++k) {
            float ev = e[k];
            dot = fmaf(q64[k], ev, dot);
            esq = fmaf(ev, ev, esq);
        }
        float d = (zz - 2.0f * dot) + esq;
        if (d < bestv) { bestv = d; besti = cc; }  // ascending cc keeps first-min
    }
    red[t] = bestv; redi[t] = besti;
    __syncthreads();
    for (int s = 64; s > 0; s >>= 1) {
        if (t < s) {
            float v = red[t + s]; int i2 = redi[t + s];
            if (v < red[t] || (v == red[t] && i2 < redi[t])) { red[t] = v; redi[t] = i2; }
        }
        __syncthreads();
    }
    const int best = redi[0];
    __syncthreads();

    // quantized, straight-through value, per-class sum of squared diffs
    if (t < 64) {
        float z  = q64[t];
        float qq = vq[best * VQD + t];
        float q_ste = z + (qq - z);   // replicate reference fp exactly
        qs[t] = q_ste;
        float dd = q_ste - z;
        red[t] = dd * dd;
    } else red[t] = 0.0f;
    __syncthreads();
    for (int s = 64; s > 0; s >>= 1) { if (t < s) red[t] += red[t + s]; __syncthreads(); }
    if (t == 0) { ms_c[c] = red[0]; id_c[c] = best; }

    // actor heads: threads 0..63 -> mean, 64..127 -> scale
    {
        const int j = t & 63;
        const float* W = (t < 64) ? Wa : Ws;
        float a2 = (t < 64) ? ba[j] : bs[j];
        #pragma unroll 16
        for (int k = 0; k < 64; ++k) a2 = fmaf(qs[k], W[k * 64 + j], a2);
        float s = sigmoidf_(a2);
        if (t < 64) am_c[c * 64 + j] = s;
        else        sd_c[c * 64 + j] = s * 1.0f + 1e-8f;   // SQUISH=1.0
    }

    // critic stack
    acc = bc0[t];
    #pragma unroll 16
    for (int k = 0; k < 64; ++k) acc = fmaf(qs[k], Wc0[k * 128 + t], acc);
    ya[t] = sigmoidf_(acc);
    __syncthreads();

    acc = bc1[t];
    #pragma unroll 16
    for (int k = 0; k < 128; ++k) acc = fmaf(ya[k], Wc1[k * 128 + t], acc);
    za[t] = sigmoidf_(acc);
    __syncthreads();

    if (t < 32) {
        float a2 = bc2[t];
        #pragma unroll 16
        for (int k = 0; k < 128; ++k) a2 = fmaf(za[k], Wc2[k * 32 + t], a2);
        q64[t] = sigmoidf_(a2);
    }
    __syncthreads();

    if (t == 0) {
        float a2 = bc3[0];
        for (int k = 0; k < 32; ++k) a2 = fmaf(q64[k], Wc3[k], a2);
        cr_c[c] = a2;
    }
}

// ---------------------------------------------------------------------------
// Kernel 2: scatter am/sd. Branch-free, float4-vectorized, fully coalesced,
// non-temporal stores (output is streaming, never re-read in-kernel).
// NO atomics, NO fences (round-3 lesson).
// ---------------------------------------------------------------------------
__global__ __launch_bounds__(256) void scatter_vec(
    const int* __restrict__ obs,
    const f32x4* __restrict__ amc, const f32x4* __restrict__ sdc,
    f32x4* __restrict__ out_am, f32x4* __restrict__ out_sd, int n4)
{
    const int e4 = blockIdx.x * 256 + threadIdx.x;
    if (e4 >= n4) return;
    const int i  = e4 >> 4;     // 16 float4 per 64-wide row
    const int d4 = e4 & 15;
    const int c  = obs[i];
    const int off = (c << 4) + d4;
    __builtin_nontemporal_store(amc[off], out_am + e4);
    __builtin_nontemporal_store(sdc[off], out_sd + e4);
}

// ---------------------------------------------------------------------------
// Kernel 3: per-row critic/idx scatter (coalesced) + class histogram
// (LDS-per-block, then scattered global atomics — round-2-proven cheap).
// ---------------------------------------------------------------------------
__global__ __launch_bounds__(256) void hist_cr_idx(
    const int* __restrict__ obs, const float* __restrict__ crc,
    const int* __restrict__ idc,
    float* __restrict__ out_cr, float* __restrict__ out_idx,
    unsigned int* __restrict__ counts, int n)
{
    __shared__ unsigned int h[NCLS];
    const int t = threadIdx.x;
    if (t < NCLS) h[t] = 0u;
    __syncthreads();
    for (int i = blockIdx.x * blockDim.x + t; i < n; i += gridDim.x * blockDim.x) {
        const int c = obs[i];
        __builtin_nontemporal_store(crc[c], out_cr + i);
        __builtin_nontemporal_store((float)idc[c], out_idx + i);
        atomicAdd(&h[c], 1u);
    }
    __syncthreads();
    if (t < NCLS) atomicAdd(&counts[t], h[t]);
}

// ---------------------------------------------------------------------------
// Kernel 4: vq_loss = (1 + COMMIT) * sum_c count_c * ssd_c / (B*64)
// ---------------------------------------------------------------------------
__global__ __launch_bounds__(128) void finalize_vq(
    const unsigned int* __restrict__ counts, const float* __restrict__ ms,
    float* __restrict__ out, int n)
{
    __shared__ double sd[128];
    const int t = threadIdx.x;
    double a = 0.0;
    if (t < NCLS) a = (double)counts[t] * (double)ms[t];
    sd[t] = a;
    __syncthreads();
    for (int s = 64; s > 0; s >>= 1) { if (t < s) sd[t] += sd[t + s]; __syncthreads(); }
    if (t == 0) out[0] = (float)(1.25 * sd[0] / ((double)n * 64.0));
}

// ---------------------------------------------------------------------------
extern "C" void kernel_launch(void* const* d_in, const int* in_sizes, int n_in,
                              void* d_out, int out_size, void* d_ws, size_t ws_size,
                              hipStream_t stream)
{
    const int*   obs   = (const int*)d_in[0];
    const float* embed = (const float*)d_in[1];
    const float* W0  = (const float*)d_in[2];   const float* b0  = (const float*)d_in[3];
    const float* W1  = (const float*)d_in[4];   const float* b1  = (const float*)d_in[5];
    const float* W2  = (const float*)d_in[6];   const float* b2  = (const float*)d_in[7];
    const float* Wp  = (const float*)d_in[8];   const float* bp  = (const float*)d_in[9];
    const float* vq  = (const float*)d_in[10];
    const float* Wa  = (const float*)d_in[11];  const float* ba  = (const float*)d_in[12];
    const float* Ws  = (const float*)d_in[13];  const float* bs  = (const float*)d_in[14];
    const float* Wc0 = (const float*)d_in[15];  const float* bc0 = (const float*)d_in[16];
    const float* Wc1 = (const float*)d_in[17];  const float* bc1 = (const float*)d_in[18];
    const float* Wc2 = (const float*)d_in[19];  const float* bc2 = (const float*)d_in[20];
    const float* Wc3 = (const float*)d_in[21];  const float* bc3 = (const float*)d_in[22];

    const int n = in_sizes[0];   // B = 262144

    // workspace layout (floats)
    float* ws_f  = (float*)d_ws;
    float* am_c  = ws_f;                 // NCLS*64
    float* sd_c  = am_c + NCLS * 64;     // NCLS*64
    float* cr_c  = sd_c + NCLS * 64;     // NCLS
    float* ms_c  = cr_c + NCLS;          // NCLS
    int*   id_c  = (int*)(ms_c + NCLS);  // NCLS
    unsigned int* counts = (unsigned int*)(id_c + NCLS);  // NCLS

    // output layout: am [n*64] | sd [n*64] | critic [n] | vq_loss [1] | idx [n]
    float* out     = (float*)d_out;
    float* out_am  = out;
    float* out_sd  = out + (size_t)n * 64;
    float* out_cr  = out + (size_t)n * 128;
    float* out_vq  = out_cr + n;
    float* out_idx = out_vq + 1;

    class_forward<<<NCLS, 128, 0, stream>>>(
        embed, W0, b0, W1, b1, W2, b2, Wp, bp, vq,
        Wa, ba, Ws, bs, Wc0, bc0, Wc1, bc1, Wc2, bc2, Wc3, bc3,
        am_c, sd_c, cr_c, ms_c, id_c, counts);

    const int n4 = n * 16;  // float4 elements per 64-wide output
    scatter_vec<<<(n4 + 255) / 256, 256, 0, stream>>>(
        obs, (const f32x4*)am_c, (const f32x4*)sd_c,
        (f32x4*)out_am, (f32x4*)out_sd, n4);

    hist_cr_idx<<<512, 256, 0, stream>>>(obs, cr_c, id_c, out_cr, out_idx, counts, n);

    finalize_vq<<<1, 128, 0, stream>>>(counts, ms_c, out_vq, n);
}

// Round 6
// 233.834 us; speedup vs baseline: 1.0938x; 1.0938x over previous
//
#include <hip/hip_runtime.h>
#include <hip/hip_bf16.h>
#include <math.h>

// Problem constants (from reference)
#define NCLS 100     // NUM_CLASSES
#define DD   128     // D
#define VQD  64      // VQ_DIM
#define VQK  512     // VQ_K

typedef float f32x4 __attribute__((ext_vector_type(4)));

__device__ __forceinline__ float sigmoidf_(float x) { return 1.0f / (1.0f + expf(-x)); }

// ---------------------------------------------------------------------------
// Kernel 1: full forward for each of the 100 classes + obs-chunk histogram.
// One block per class, 128 threads. Weights L2-resident (~0.4 MB).
// Block c histograms obs[c*chunk .. ) into its PRIVATE row hist_part[c][.]
// (no global atomics, no cross-block races).
// ---------------------------------------------------------------------------
__global__ __launch_bounds__(128) void class_forward(
    const float* __restrict__ embed,
    const float* __restrict__ W0, const float* __restrict__ b0,
    const float* __restrict__ W1, const float* __restrict__ b1,
    const float* __restrict__ W2, const float* __restrict__ b2,
    const float* __restrict__ Wp, const float* __restrict__ bp,
    const float* __restrict__ vq,
    const float* __restrict__ Wa, const float* __restrict__ ba,
    const float* __restrict__ Ws, const float* __restrict__ bs,
    const float* __restrict__ Wc0, const float* __restrict__ bc0,
    const float* __restrict__ Wc1, const float* __restrict__ bc1,
    const float* __restrict__ Wc2, const float* __restrict__ bc2,
    const float* __restrict__ Wc3, const float* __restrict__ bc3,
    const int* __restrict__ obs, int nn,
    float* __restrict__ am_c, float* __restrict__ sd_c,
    float* __restrict__ cr_c, float* __restrict__ ms_c, int* __restrict__ id_c,
    unsigned int* __restrict__ hist_part)
{
    __shared__ float ya[128], za[128], q64[64], qs[64], red[128];
    __shared__ int   redi[128];
    __shared__ unsigned int h[NCLS];
    const int c = blockIdx.x;
    const int t = threadIdx.x;

    // embedding lookup
    ya[t] = embed[c * DD + t];
    if (t < NCLS) h[t] = 0u;
    __syncthreads();

    // 3x dense(128->128) + relu
    float acc = b0[t];
    #pragma unroll 16
    for (int k = 0; k < 128; ++k) acc = fmaf(ya[k], W0[k * 128 + t], acc);
    za[t] = fmaxf(acc, 0.0f);
    __syncthreads();

    acc = b1[t];
    #pragma unroll 16
    for (int k = 0; k < 128; ++k) acc = fmaf(za[k], W1[k * 128 + t], acc);
    ya[t] = fmaxf(acc, 0.0f);
    __syncthreads();

    acc = b2[t];
    #pragma unroll 16
    for (int k = 0; k < 128; ++k) acc = fmaf(ya[k], W2[k * 128 + t], acc);
    za[t] = fmaxf(acc, 0.0f);
    __syncthreads();

    // projection 128 -> 64 (no activation)
    if (t < 64) {
        float a2 = bp[t];
        #pragma unroll 16
        for (int k = 0; k < 128; ++k) a2 = fmaf(za[k], Wp[k * 64 + t], a2);
        q64[t] = a2;
    }
    __syncthreads();

    // ||z||^2 (constant per row, but reference includes it in the argmin key)
    if (t < 64) { red[t] = q64[t] * q64[t]; } else red[t] = 0.0f;
    __syncthreads();
    for (int s = 64; s > 0; s >>= 1) { if (t < s) red[t] += red[t + s]; __syncthreads(); }
    const float zz = red[0];
    __syncthreads();

    // VQ argmin over 512 codes; full key d = (zz - 2 z.e) + ||e||^2 (reference order)
    float bestv = 3.4e38f;
    int   besti = 0;
    for (int cc = t; cc < VQK; cc += 128) {
        const float* e = vq + cc * VQD;
        float dot = 0.0f, esq = 0.0f;
        #pragma unroll 16
        for (int k = 0; k < VQD; ++k) {
            float ev = e[k];
            dot = fmaf(q64[k], ev, dot);
            esq = fmaf(ev, ev, esq);
        }
        float d = (zz - 2.0f * dot) + esq;
        if (d < bestv) { bestv = d; besti = cc; }  // ascending cc keeps first-min
    }
    red[t] = bestv; redi[t] = besti;
    __syncthreads();
    for (int s = 64; s > 0; s >>= 1) {
        if (t < s) {
            float v = red[t + s]; int i2 = redi[t + s];
            if (v < red[t] || (v == red[t] && i2 < redi[t])) { red[t] = v; redi[t] = i2; }
        }
        __syncthreads();
    }
    const int best = redi[0];
    __syncthreads();

    // quantized, straight-through value, per-class sum of squared diffs
    if (t < 64) {
        float z  = q64[t];
        float qq = vq[best * VQD + t];
        float q_ste = z + (qq - z);   // replicate reference fp exactly
        qs[t] = q_ste;
        float dd = q_ste - z;
        red[t] = dd * dd;
    } else red[t] = 0.0f;
    __syncthreads();
    for (int s = 64; s > 0; s >>= 1) { if (t < s) red[t] += red[t + s]; __syncthreads(); }
    if (t == 0) { ms_c[c] = red[0]; id_c[c] = best; }

    // actor heads: threads 0..63 -> mean, 64..127 -> scale
    {
        const int j = t & 63;
        const float* W = (t < 64) ? Wa : Ws;
        float a2 = (t < 64) ? ba[j] : bs[j];
        #pragma unroll 16
        for (int k = 0; k < 64; ++k) a2 = fmaf(qs[k], W[k * 64 + j], a2);
        float s = sigmoidf_(a2);
        if (t < 64) am_c[c * 64 + j] = s;
        else        sd_c[c * 64 + j] = s * 1.0f + 1e-8f;   // SQUISH=1.0
    }

    // critic stack
    acc = bc0[t];
    #pragma unroll 16
    for (int k = 0; k < 64; ++k) acc = fmaf(qs[k], Wc0[k * 128 + t], acc);
    ya[t] = sigmoidf_(acc);
    __syncthreads();

    acc = bc1[t];
    #pragma unroll 16
    for (int k = 0; k < 128; ++k) acc = fmaf(ya[k], Wc1[k * 128 + t], acc);
    za[t] = sigmoidf_(acc);
    __syncthreads();

    if (t < 32) {
        float a2 = bc2[t];
        #pragma unroll 16
        for (int k = 0; k < 128; ++k) a2 = fmaf(za[k], Wc2[k * 32 + t], a2);
        q64[t] = sigmoidf_(a2);
    }
    __syncthreads();

    if (t == 0) {
        float a2 = bc3[0];
        for (int k = 0; k < 32; ++k) a2 = fmaf(q64[k], Wc3[k], a2);
        cr_c[c] = a2;
    }

    // --- obs-chunk histogram: block c owns chunk c, private output row ---
    const int chunk = (nn + NCLS - 1) / NCLS;
    const int i0 = c * chunk;
    int i1 = i0 + chunk; if (i1 > nn) i1 = nn;
    for (int i = i0 + t; i < i1; i += 128) atomicAdd(&h[obs[i]], 1u);
    __syncthreads();
    if (t < NCLS) hist_part[c * NCLS + t] = h[t];
}

// ---------------------------------------------------------------------------
// Kernel 2: scatter ALL per-row outputs (float4, coalesced; d4==0 lane also
// writes critic + idx). Block 0 additionally reduces hist_part x ms_c into
// vq_loss (inputs complete by stream order; no atomics, no fences).
// ---------------------------------------------------------------------------
__global__ __launch_bounds__(256) void scatter_all(
    const int* __restrict__ obs,
    const f32x4* __restrict__ amc, const f32x4* __restrict__ sdc,
    const float* __restrict__ crc,  const int* __restrict__ idc,
    const float* __restrict__ msc,  const unsigned int* __restrict__ hist_part,
    f32x4* __restrict__ out_am, f32x4* __restrict__ out_sd,
    float* __restrict__ out_cr,  float* __restrict__ out_idx,
    float* __restrict__ out_vq, int n4, int n)
{
    const int t  = threadIdx.x;
    const int e4 = blockIdx.x * 256 + t;
    if (e4 < n4) {
        const int i  = e4 >> 4;     // 16 float4 per 64-wide row
        const int d4 = e4 & 15;
        const int c  = obs[i];
        const int off = (c << 4) + d4;
        out_am[e4] = amc[off];
        out_sd[e4] = sdc[off];
        if (d4 == 0) {
            out_cr[i]  = crc[c];
            out_idx[i] = (float)idc[c];
        }
    }
    if (blockIdx.x == 0) {
        __shared__ double sd_[128];
        double a = 0.0;
        if (t < NCLS) {
            unsigned int cnt = 0u;
            for (int b = 0; b < NCLS; ++b) cnt += hist_part[b * NCLS + t];
            a = (double)cnt * (double)msc[t];
        }
        if (t < 128) sd_[t] = a;
        __syncthreads();
        for (int s = 64; s > 0; s >>= 1) { if (t < s) sd_[t] += sd_[t + s]; __syncthreads(); }
        if (t == 0) out_vq[0] = (float)(1.25 * sd_[0] / ((double)n * 64.0));
    }
}

// ---------------------------------------------------------------------------
extern "C" void kernel_launch(void* const* d_in, const int* in_sizes, int n_in,
                              void* d_out, int out_size, void* d_ws, size_t ws_size,
                              hipStream_t stream)
{
    const int*   obs   = (const int*)d_in[0];
    const float* embed = (const float*)d_in[1];
    const float* W0  = (const float*)d_in[2];   const float* b0  = (const float*)d_in[3];
    const float* W1  = (const float*)d_in[4];   const float* b1  = (const float*)d_in[5];
    const float* W2  = (const float*)d_in[6];   const float* b2  = (const float*)d_in[7];
    const float* Wp  = (const float*)d_in[8];   const float* bp  = (const float*)d_in[9];
    const float* vq  = (const float*)d_in[10];
    const float* Wa  = (const float*)d_in[11];  const float* ba  = (const float*)d_in[12];
    const float* Ws  = (const float*)d_in[13];  const float* bs  = (const float*)d_in[14];
    const float* Wc0 = (const float*)d_in[15];  const float* bc0 = (const float*)d_in[16];
    const float* Wc1 = (const float*)d_in[17];  const float* bc1 = (const float*)d_in[18];
    const float* Wc2 = (const float*)d_in[19];  const float* bc2 = (const float*)d_in[20];
    const float* Wc3 = (const float*)d_in[21];  const float* bc3 = (const float*)d_in[22];

    const int n = in_sizes[0];   // B = 262144

    // workspace layout (floats / uints)
    float* ws_f  = (float*)d_ws;
    float* am_c  = ws_f;                 // NCLS*64
    float* sd_c  = am_c + NCLS * 64;     // NCLS*64
    float* cr_c  = sd_c + NCLS * 64;     // NCLS
    float* ms_c  = cr_c + NCLS;          // NCLS
    int*   id_c  = (int*)(ms_c + NCLS);  // NCLS
    unsigned int* hist_part = (unsigned int*)(id_c + NCLS);  // NCLS*NCLS

    // output layout: am [n*64] | sd [n*64] | critic [n] | vq_loss [1] | idx [n]
    float* out     = (float*)d_out;
    float* out_am  = out;
    float* out_sd  = out + (size_t)n * 64;
    float* out_cr  = out + (size_t)n * 128;
    float* out_vq  = out_cr + n;
    float* out_idx = out_vq + 1;

    class_forward<<<NCLS, 128, 0, stream>>>(
        embed, W0, b0, W1, b1, W2, b2, Wp, bp, vq,
        Wa, ba, Ws, bs, Wc0, bc0, Wc1, bc1, Wc2, bc2, Wc3, bc3,
        obs, n,
        am_c, sd_c, cr_c, ms_c, id_c, hist_part);

    const int n4 = n * 16;  // float4 elements per 64-wide output
    scatter_all<<<(n4 + 255) / 256, 256, 0, stream>>>(
        obs, (const f32x4*)am_c, (const f32x4*)sd_c, cr_c, id_c, ms_c, hist_part,
        (f32x4*)out_am, (f32x4*)out_sd, out_cr, out_idx, out_vq, n4, n);
}